// Round 1
// baseline (681.750 us; speedup 1.0000x reference)
//
#include <hip/hip_runtime.h>
#include <math.h>

// ---------------------------------------------------------------------------
// GAT 2-layer (PyG GATConv eval) on gfx950.
// Strategy: build CSR by dst once (shared by both layers), then per-node
// wave-parallel edge-softmax + aggregation with zero float atomics.
// ---------------------------------------------------------------------------

// ---- CSR build ------------------------------------------------------------

__global__ void count_edges_kernel(const int* __restrict__ ei, int E, int Nn,
                                   int* __restrict__ deg) {
  int e = blockIdx.x * blockDim.x + threadIdx.x;
  int Et = E + Nn;
  if (e >= Et) return;
  int dst = (e < E) ? ei[E + e] : (e - E);  // self-loops appended
  atomicAdd(&deg[dst], 1);
}

__global__ void scan_kernel(const int* __restrict__ deg, int* __restrict__ rowptr,
                            int* __restrict__ cursor, int Nn) {
  __shared__ int sums[1024];
  int t = threadIdx.x;
  int chunk = (Nn + 1023) / 1024;
  int lo = min(t * chunk, Nn);
  int hi = min(lo + chunk, Nn);
  int s = 0;
  for (int i = lo; i < hi; ++i) s += deg[i];
  sums[t] = s;
  __syncthreads();
  // Hillis-Steele inclusive scan over 1024 partials
  for (int off = 1; off < 1024; off <<= 1) {
    int v = (t >= off) ? sums[t - off] : 0;
    __syncthreads();
    sums[t] += v;
    __syncthreads();
  }
  int excl = (t == 0) ? 0 : sums[t - 1];
  for (int i = lo; i < hi; ++i) {
    rowptr[i] = excl;
    cursor[i] = excl;
    excl += deg[i];
  }
  if (t == 1023) rowptr[Nn] = sums[1023];
}

__global__ void scatter_edges_kernel(const int* __restrict__ ei, int E, int Nn,
                                     int* __restrict__ cursor, int* __restrict__ col) {
  int e = blockIdx.x * blockDim.x + threadIdx.x;
  if (e >= E + Nn) return;
  int src, dst;
  if (e < E) { src = ei[e]; dst = ei[E + e]; }
  else       { src = dst = e - E; }
  int pos = atomicAdd(&cursor[dst], 1);
  col[pos] = src;
}

// ---- tiled fp32 GEMM: C[MxN] = A[MxK] @ B[KxN], row-major ------------------

#define GBM 64
#define GBN 64
#define GBK 16

__global__ void sgemm_kernel(const float* __restrict__ A, const float* __restrict__ B,
                             float* __restrict__ C, int M, int N, int K) {
  __shared__ float As[GBK][GBM + 4];  // transposed A tile, padded
  __shared__ float Bs[GBK][GBN];
  int tid = threadIdx.x;          // 256 threads
  int tx = tid % 16, ty = tid / 16;
  int bm0 = blockIdx.x * GBM;
  int bn0 = blockIdx.y * GBN;

  int ar = tid / 4;               // 0..63  (row within A tile)
  int ac = (tid % 4) * 4;         // 0,4,8,12 (k within tile)
  int br = tid / 16;              // 0..15  (k within tile)
  int bc = (tid % 16) * 4;        // 0..60  (col within tile)

  float acc[4][4] = {};

  for (int k0 = 0; k0 < K; k0 += GBK) {
    float4 av = make_float4(0.f, 0.f, 0.f, 0.f);
    if (bm0 + ar < M)
      av = *(const float4*)(A + (size_t)(bm0 + ar) * K + k0 + ac);
    As[ac + 0][ar] = av.x;
    As[ac + 1][ar] = av.y;
    As[ac + 2][ar] = av.z;
    As[ac + 3][ar] = av.w;

    float4 bv = *(const float4*)(B + (size_t)(k0 + br) * N + bn0 + bc);
    *(float4*)&Bs[br][bc] = bv;
    __syncthreads();

#pragma unroll
    for (int k = 0; k < GBK; ++k) {
      float4 a4 = *(const float4*)&As[k][ty * 4];
      float4 b4 = *(const float4*)&Bs[k][tx * 4];
      float avr[4] = {a4.x, a4.y, a4.z, a4.w};
      float bvr[4] = {b4.x, b4.y, b4.z, b4.w};
#pragma unroll
      for (int i = 0; i < 4; ++i)
#pragma unroll
        for (int j = 0; j < 4; ++j)
          acc[i][j] = fmaf(avr[i], bvr[j], acc[i][j]);
    }
    __syncthreads();
  }

#pragma unroll
  for (int i = 0; i < 4; ++i) {
    int row = bm0 + ty * 4 + i;
    if (row < M) {
      float4 o = make_float4(acc[i][0], acc[i][1], acc[i][2], acc[i][3]);
      *(float4*)(C + (size_t)row * N + bn0 + tx * 4) = o;
    }
  }
}

// ---- per-node attention coefficients: alpha[n,h] = dot(xl[n,h,:], a[h,:]) --

__global__ void alpha_kernel(const float* __restrict__ xl,
                             const float* __restrict__ a_src,
                             const float* __restrict__ a_dst,
                             float* __restrict__ asrc, float* __restrict__ adst,
                             int Nn, int H, int C) {
  int idx = blockIdx.x * blockDim.x + threadIdx.x;  // (n,h)
  if (idx >= Nn * H) return;
  int h = idx % H;
  const float* row = xl + (size_t)idx * C;  // idx = n*H+h, xl row-major [N,H,C]
  const float* as = a_src + h * C;
  const float* ad = a_dst + h * C;
  float ssum = 0.f, dsum = 0.f;
  for (int c = 0; c < C; c += 4) {
    float4 v = *(const float4*)(row + c);
    float4 a = *(const float4*)(as + c);
    float4 d = *(const float4*)(ad + c);
    ssum += v.x * a.x + v.y * a.y + v.z * a.z + v.w * a.w;
    dsum += v.x * d.x + v.y * d.y + v.z * d.z + v.w * d.w;
  }
  asrc[idx] = ssum;
  adst[idx] = dsum;
}

// ---- layer-1 aggregation: H=4, C=64, wave per node, lane = 4 channels ------
// epilogue: + bias, ELU

__global__ void agg_multi_kernel(const float* __restrict__ xl,
                                 const float* __restrict__ asrc,
                                 const float* __restrict__ adst,
                                 const int* __restrict__ rowptr,
                                 const int* __restrict__ col,
                                 const float* __restrict__ bias,
                                 float* __restrict__ out, int Nn) {
  int n = blockIdx.x * (blockDim.x >> 6) + (threadIdx.x >> 6);
  if (n >= Nn) return;
  int lane = threadIdx.x & 63;
  int h = lane >> 4;                         // head of this lane's 4 channels
  float adst_n = adst[n * 4 + h];
  int beg = rowptr[n], end = rowptr[n + 1];

  // online softmax (max + rescaled sum); every node has >=1 edge (self-loop)
  float m = -INFINITY, s = 0.f;
  for (int i = beg; i < end; ++i) {
    int sc = col[i];
    float e = asrc[sc * 4 + h] + adst_n;
    e = (e > 0.f) ? e : 0.2f * e;            // leaky_relu 0.2
    float mn = fmaxf(m, e);
    s = s * expf(m - mn) + expf(e - mn);
    m = mn;
  }
  float inv_s = 1.f / s;

  float4 acc = make_float4(0.f, 0.f, 0.f, 0.f);
  for (int i = beg; i < end; ++i) {
    int sc = col[i];
    float e = asrc[sc * 4 + h] + adst_n;
    e = (e > 0.f) ? e : 0.2f * e;
    float alpha = expf(e - m) * inv_s;
    float4 v = *(const float4*)(xl + (size_t)sc * 256 + lane * 4);
    acc.x = fmaf(v.x, alpha, acc.x);
    acc.y = fmaf(v.y, alpha, acc.y);
    acc.z = fmaf(v.z, alpha, acc.z);
    acc.w = fmaf(v.w, alpha, acc.w);
  }

  float4 b = *(const float4*)(bias + lane * 4);
  float4 o;
  o.x = acc.x + b.x; o.y = acc.y + b.y; o.z = acc.z + b.z; o.w = acc.w + b.w;
  o.x = (o.x > 0.f) ? o.x : expf(o.x) - 1.f;  // ELU
  o.y = (o.y > 0.f) ? o.y : expf(o.y) - 1.f;
  o.z = (o.z > 0.f) ? o.z : expf(o.z) - 1.f;
  o.w = (o.w > 0.f) ? o.w : expf(o.w) - 1.f;
  *(float4*)(out + (size_t)n * 256 + lane * 4) = o;
}

// ---- layer-2 aggregation: H=1, C=64, wave per node, lane = channel ---------
// epilogue: + bias (mean over 1 head = identity)

__global__ void agg_single_kernel(const float* __restrict__ xl,
                                  const float* __restrict__ asrc,
                                  const float* __restrict__ adst,
                                  const int* __restrict__ rowptr,
                                  const int* __restrict__ col,
                                  const float* __restrict__ bias,
                                  float* __restrict__ out, int Nn) {
  int n = blockIdx.x * (blockDim.x >> 6) + (threadIdx.x >> 6);
  if (n >= Nn) return;
  int lane = threadIdx.x & 63;
  float adst_n = adst[n];
  int beg = rowptr[n], end = rowptr[n + 1];

  float m = -INFINITY, s = 0.f;
  for (int i = beg; i < end; ++i) {
    int sc = col[i];
    float e = asrc[sc] + adst_n;
    e = (e > 0.f) ? e : 0.2f * e;
    float mn = fmaxf(m, e);
    s = s * expf(m - mn) + expf(e - mn);
    m = mn;
  }
  float inv_s = 1.f / s;

  float acc = 0.f;
  for (int i = beg; i < end; ++i) {
    int sc = col[i];
    float e = asrc[sc] + adst_n;
    e = (e > 0.f) ? e : 0.2f * e;
    float alpha = expf(e - m) * inv_s;
    acc = fmaf(xl[(size_t)sc * 64 + lane], alpha, acc);
  }
  out[(size_t)n * 64 + lane] = acc + bias[lane];
}

// ---------------------------------------------------------------------------

extern "C" void kernel_launch(void* const* d_in, const int* in_sizes, int n_in,
                              void* d_out, int out_size, void* d_ws, size_t ws_size,
                              hipStream_t stream) {
  const float* x   = (const float*)d_in[0];
  const int*   ei  = (const int*)d_in[1];   // edge_index [2,E], int32 per harness
  const float* W1  = (const float*)d_in[2];
  const float* as1 = (const float*)d_in[3];
  const float* ad1 = (const float*)d_in[4];
  const float* b1  = (const float*)d_in[5];
  const float* W2  = (const float*)d_in[6];
  const float* as2 = (const float*)d_in[7];
  const float* ad2 = (const float*)d_in[8];
  const float* b2  = (const float*)d_in[9];
  float* out = (float*)d_out;

  const int Nn = in_sizes[0] / 128;  // 50000
  const int E  = in_sizes[1] / 2;    // 800000
  const int Et = E + Nn;

  // workspace layout (256B-aligned chunks)
  char* base = (char*)d_ws;
  size_t off = 0;
  auto alloc = [&](size_t bytes) -> void* {
    void* p = base + off;
    off = (off + bytes + 255) & ~(size_t)255;
    return p;
  };
  float* xl1    = (float*)alloc((size_t)Nn * 256 * 4);  // layer1 x@W1 [N,256]
  float* hbuf   = (float*)alloc((size_t)Nn * 256 * 4);  // ELU output  [N,256]
  float* asrc1  = (float*)alloc((size_t)Nn * 4 * 4);
  float* adst1  = (float*)alloc((size_t)Nn * 4 * 4);
  float* asrc2  = (float*)alloc((size_t)Nn * 4);
  float* adst2  = (float*)alloc((size_t)Nn * 4);
  int*   deg    = (int*)alloc((size_t)Nn * 4);
  int*   rowptr = (int*)alloc((size_t)(Nn + 1) * 4);
  int*   cursor = (int*)alloc((size_t)Nn * 4);
  int*   col    = (int*)alloc((size_t)Et * 4);
  float* xl2 = xl1;  // layer2 h@W2 [N,64] aliases xl1 (dead after layer1 agg)

  // --- CSR build (shared by both layers) ---
  hipMemsetAsync(deg, 0, (size_t)Nn * 4, stream);
  count_edges_kernel<<<(Et + 255) / 256, 256, 0, stream>>>(ei, E, Nn, deg);
  scan_kernel<<<1, 1024, 0, stream>>>(deg, rowptr, cursor, Nn);
  scatter_edges_kernel<<<(Et + 255) / 256, 256, 0, stream>>>(ei, E, Nn, cursor, col);

  // --- layer 1 ---
  {
    dim3 grid((Nn + GBM - 1) / GBM, 256 / GBN);
    sgemm_kernel<<<grid, 256, 0, stream>>>(x, W1, xl1, Nn, 256, 128);
  }
  alpha_kernel<<<(Nn * 4 + 255) / 256, 256, 0, stream>>>(xl1, as1, ad1, asrc1, adst1, Nn, 4, 64);
  agg_multi_kernel<<<(Nn + 3) / 4, 256, 0, stream>>>(xl1, asrc1, adst1, rowptr, col, b1, hbuf, Nn);

  // --- layer 2 ---
  {
    dim3 grid((Nn + GBM - 1) / GBM, 64 / GBN);
    sgemm_kernel<<<grid, 256, 0, stream>>>(hbuf, W2, xl2, Nn, 64, 256);
  }
  alpha_kernel<<<(Nn + 255) / 256, 256, 0, stream>>>(xl2, as2, ad2, asrc2, adst2, Nn, 1, 64);
  agg_single_kernel<<<(Nn + 3) / 4, 256, 0, stream>>>(xl2, asrc2, adst2, rowptr, col, b2, out, Nn);
}

// Round 2
// 541.706 us; speedup vs baseline: 1.2585x; 1.2585x over previous
//
#include <hip/hip_runtime.h>
#include <math.h>

// ---------------------------------------------------------------------------
// GAT 2-layer (PyG GATConv eval) on gfx950.
// R2: single-pass online-softmax aggregation (+prefetch, __expf),
//     tuned fp32 tiled SGEMM (128x128x16 / 128x64x32, 8x8 / 8x4 per thread).
// ---------------------------------------------------------------------------

// ---- CSR build ------------------------------------------------------------

__global__ void count_edges_kernel(const int* __restrict__ ei, int E, int Nn,
                                   int* __restrict__ deg) {
  int e = blockIdx.x * blockDim.x + threadIdx.x;
  int Et = E + Nn;
  if (e >= Et) return;
  int dst = (e < E) ? ei[E + e] : (e - E);  // self-loops appended
  atomicAdd(&deg[dst], 1);
}

__global__ void scan_kernel(const int* __restrict__ deg, int* __restrict__ rowptr,
                            int* __restrict__ cursor, int Nn) {
  __shared__ int sums[1024];
  int t = threadIdx.x;
  int chunk = (Nn + 1023) / 1024;
  int lo = min(t * chunk, Nn);
  int hi = min(lo + chunk, Nn);
  int s = 0;
  for (int i = lo; i < hi; ++i) s += deg[i];
  sums[t] = s;
  __syncthreads();
  for (int off = 1; off < 1024; off <<= 1) {
    int v = (t >= off) ? sums[t - off] : 0;
    __syncthreads();
    sums[t] += v;
    __syncthreads();
  }
  int excl = (t == 0) ? 0 : sums[t - 1];
  for (int i = lo; i < hi; ++i) {
    rowptr[i] = excl;
    cursor[i] = excl;
    excl += deg[i];
  }
  if (t == 1023) rowptr[Nn] = sums[1023];
}

__global__ void scatter_edges_kernel(const int* __restrict__ ei, int E, int Nn,
                                     int* __restrict__ cursor, int* __restrict__ col) {
  int e = blockIdx.x * blockDim.x + threadIdx.x;
  if (e >= E + Nn) return;
  int src, dst;
  if (e < E) { src = ei[e]; dst = ei[E + e]; }
  else       { src = dst = e - E; }
  int pos = atomicAdd(&cursor[dst], 1);
  col[pos] = src;
}

// ---- tiled fp32 GEMM: C[MxN] = A[MxK] @ B[KxN], row-major ------------------
// 256 threads; TM=8 (rows split 4+4 at BM/2), TN = 4*TNSPL (cols split at BN/2
// when TNSPL=2). Split fragments keep ds_read_b128 at <=2-way bank aliasing.

template <int BM, int BN, int BK, int TNSPL>
__global__ __launch_bounds__(256) void sgemm_kernel(
    const float* __restrict__ A, const float* __restrict__ B,
    float* __restrict__ C, int M, int N, int K) {
  constexpr int TN = 4 * TNSPL;
  constexpr int NTX = BN / TN;        // 16
  constexpr int NTY = 256 / NTX;      // 16
  static_assert(BM / NTY == 8, "TM must be 8");
  constexpr int APASS = BM * BK / 1024;
  constexpr int BPASS = BK * BN / 1024;

  __shared__ float As[BK][BM + 4];    // transposed A tile
  __shared__ float Bs[BK][BN];

  int tid = threadIdx.x;
  int tx = tid % NTX, ty = tid / NTX;
  int bm0 = blockIdx.x * BM, bn0 = blockIdx.y * BN;

  float acc[8][TN] = {};

  for (int k0 = 0; k0 < K; k0 += BK) {
#pragma unroll
    for (int p = 0; p < APASS; ++p) {
      int lin = p * 1024 + tid * 4;
      int r = lin / BK, c = lin % BK;
      float4 av = make_float4(0.f, 0.f, 0.f, 0.f);
      if (bm0 + r < M)
        av = *(const float4*)(A + (size_t)(bm0 + r) * K + k0 + c);
      As[c + 0][r] = av.x;
      As[c + 1][r] = av.y;
      As[c + 2][r] = av.z;
      As[c + 3][r] = av.w;
    }
#pragma unroll
    for (int p = 0; p < BPASS; ++p) {
      int lin = p * 1024 + tid * 4;
      int r = lin / BN, c = lin % BN;
      *(float4*)&Bs[r][c] = *(const float4*)(B + (size_t)(k0 + r) * N + bn0 + c);
    }
    __syncthreads();

#pragma unroll
    for (int k = 0; k < BK; ++k) {
      float a[8], b[TN];
      *(float4*)&a[0] = *(const float4*)&As[k][ty * 4];
      *(float4*)&a[4] = *(const float4*)&As[k][BM / 2 + ty * 4];
      *(float4*)&b[0] = *(const float4*)&Bs[k][tx * 4];
      if constexpr (TNSPL == 2)
        *(float4*)&b[4] = *(const float4*)&Bs[k][BN / 2 + tx * 4];
#pragma unroll
      for (int i = 0; i < 8; ++i)
#pragma unroll
        for (int j = 0; j < TN; ++j)
          acc[i][j] = fmaf(a[i], b[j], acc[i][j]);
    }
    __syncthreads();
  }

#pragma unroll
  for (int i = 0; i < 8; ++i) {
    int row = bm0 + ((i < 4) ? (ty * 4 + i) : (BM / 2 + ty * 4 + i - 4));
    if (row < M) {
      *(float4*)(C + (size_t)row * N + bn0 + tx * 4) =
          make_float4(acc[i][0], acc[i][1], acc[i][2], acc[i][3]);
      if constexpr (TNSPL == 2)
        *(float4*)(C + (size_t)row * N + bn0 + BN / 2 + tx * 4) =
            make_float4(acc[i][4], acc[i][5], acc[i][6], acc[i][7]);
    }
  }
}

// ---- per-node attention coefficients ---------------------------------------

__global__ void alpha_kernel(const float* __restrict__ xl,
                             const float* __restrict__ a_src,
                             const float* __restrict__ a_dst,
                             float* __restrict__ asrc, float* __restrict__ adst,
                             int Nn, int H, int C) {
  int idx = blockIdx.x * blockDim.x + threadIdx.x;  // (n,h)
  if (idx >= Nn * H) return;
  int h = idx % H;
  const float* row = xl + (size_t)idx * C;
  const float* as = a_src + h * C;
  const float* ad = a_dst + h * C;
  float ssum = 0.f, dsum = 0.f;
  for (int c = 0; c < C; c += 4) {
    float4 v = *(const float4*)(row + c);
    float4 a = *(const float4*)(as + c);
    float4 d = *(const float4*)(ad + c);
    ssum += v.x * a.x + v.y * a.y + v.z * a.z + v.w * a.w;
    dsum += v.x * d.x + v.y * d.y + v.z * d.z + v.w * d.w;
  }
  asrc[idx] = ssum;
  adst[idx] = dsum;
}

// ---- layer-1 aggregation: H=4, C=64, wave/node, single-pass online softmax --

__global__ void agg_multi_kernel(const float* __restrict__ xl,
                                 const float* __restrict__ asrc,
                                 const float* __restrict__ adst,
                                 const int* __restrict__ rowptr,
                                 const int* __restrict__ col,
                                 const float* __restrict__ bias,
                                 float* __restrict__ out, int Nn) {
  int n = blockIdx.x * (blockDim.x >> 6) + (threadIdx.x >> 6);
  if (n >= Nn) return;
  int lane = threadIdx.x & 63;
  int h = lane >> 4;
  float adst_n = adst[n * 4 + h];
  int beg = rowptr[n], end = rowptr[n + 1];

  float m = -INFINITY, s = 0.f;
  float4 acc = make_float4(0.f, 0.f, 0.f, 0.f);

  // prefetch edge 0 (every node has >=1 edge: self-loop)
  int sc = col[beg];
  float as = asrc[sc * 4 + h];
  float4 v = *(const float4*)(xl + (size_t)sc * 256 + lane * 4);

  for (int i = beg; i < end; ++i) {
    float e = as + adst_n;
    e = (e > 0.f) ? e : 0.2f * e;            // leaky_relu 0.2
    float4 vc = v;
    if (i + 1 < end) {                        // prefetch next edge
      int sc2 = col[i + 1];
      as = asrc[sc2 * 4 + h];
      v = *(const float4*)(xl + (size_t)sc2 * 256 + lane * 4);
    }
    float mn = fmaxf(m, e);
    float r = __expf(m - mn);                 // 0 on first iter (m=-inf)
    float w = __expf(e - mn);
    s = fmaf(s, r, w);
    acc.x = fmaf(acc.x, r, w * vc.x);
    acc.y = fmaf(acc.y, r, w * vc.y);
    acc.z = fmaf(acc.z, r, w * vc.z);
    acc.w = fmaf(acc.w, r, w * vc.w);
    m = mn;
  }
  float inv_s = 1.f / s;

  float4 b = *(const float4*)(bias + lane * 4);
  float4 o;
  o.x = fmaf(acc.x, inv_s, b.x);
  o.y = fmaf(acc.y, inv_s, b.y);
  o.z = fmaf(acc.z, inv_s, b.z);
  o.w = fmaf(acc.w, inv_s, b.w);
  o.x = (o.x > 0.f) ? o.x : __expf(o.x) - 1.f;  // ELU
  o.y = (o.y > 0.f) ? o.y : __expf(o.y) - 1.f;
  o.z = (o.z > 0.f) ? o.z : __expf(o.z) - 1.f;
  o.w = (o.w > 0.f) ? o.w : __expf(o.w) - 1.f;
  *(float4*)(out + (size_t)n * 256 + lane * 4) = o;
}

// ---- layer-2 aggregation: H=1, C=64, wave/node, single-pass online softmax --

__global__ void agg_single_kernel(const float* __restrict__ xl,
                                  const float* __restrict__ asrc,
                                  const float* __restrict__ adst,
                                  const int* __restrict__ rowptr,
                                  const int* __restrict__ col,
                                  const float* __restrict__ bias,
                                  float* __restrict__ out, int Nn) {
  int n = blockIdx.x * (blockDim.x >> 6) + (threadIdx.x >> 6);
  if (n >= Nn) return;
  int lane = threadIdx.x & 63;
  float adst_n = adst[n];
  int beg = rowptr[n], end = rowptr[n + 1];

  float m = -INFINITY, s = 0.f, acc = 0.f;

  int sc = col[beg];
  float as = asrc[sc];
  float v = xl[(size_t)sc * 64 + lane];

  for (int i = beg; i < end; ++i) {
    float e = as + adst_n;
    e = (e > 0.f) ? e : 0.2f * e;
    float vc = v;
    if (i + 1 < end) {
      int sc2 = col[i + 1];
      as = asrc[sc2];
      v = xl[(size_t)sc2 * 64 + lane];
    }
    float mn = fmaxf(m, e);
    float r = __expf(m - mn);
    float w = __expf(e - mn);
    s = fmaf(s, r, w);
    acc = fmaf(acc, r, w * vc);
    m = mn;
  }
  out[(size_t)n * 64 + lane] = fmaf(acc, 1.f / s, bias[lane]);
}

// ---------------------------------------------------------------------------

extern "C" void kernel_launch(void* const* d_in, const int* in_sizes, int n_in,
                              void* d_out, int out_size, void* d_ws, size_t ws_size,
                              hipStream_t stream) {
  const float* x   = (const float*)d_in[0];
  const int*   ei  = (const int*)d_in[1];
  const float* W1  = (const float*)d_in[2];
  const float* as1 = (const float*)d_in[3];
  const float* ad1 = (const float*)d_in[4];
  const float* b1  = (const float*)d_in[5];
  const float* W2  = (const float*)d_in[6];
  const float* as2 = (const float*)d_in[7];
  const float* ad2 = (const float*)d_in[8];
  const float* b2  = (const float*)d_in[9];
  float* out = (float*)d_out;

  const int Nn = in_sizes[0] / 128;  // 50000
  const int E  = in_sizes[1] / 2;    // 800000
  const int Et = E + Nn;

  char* base = (char*)d_ws;
  size_t off = 0;
  auto alloc = [&](size_t bytes) -> void* {
    void* p = base + off;
    off = (off + bytes + 255) & ~(size_t)255;
    return p;
  };
  float* xl1    = (float*)alloc((size_t)Nn * 256 * 4);
  float* hbuf   = (float*)alloc((size_t)Nn * 256 * 4);
  float* asrc1  = (float*)alloc((size_t)Nn * 4 * 4);
  float* adst1  = (float*)alloc((size_t)Nn * 4 * 4);
  float* asrc2  = (float*)alloc((size_t)Nn * 4);
  float* adst2  = (float*)alloc((size_t)Nn * 4);
  int*   deg    = (int*)alloc((size_t)Nn * 4);
  int*   rowptr = (int*)alloc((size_t)(Nn + 1) * 4);
  int*   cursor = (int*)alloc((size_t)Nn * 4);
  int*   col    = (int*)alloc((size_t)Et * 4);
  float* xl2 = xl1;  // layer-2 x@W2 aliases xl1 (dead after layer-1 agg)

  // --- CSR build (shared by both layers) ---
  hipMemsetAsync(deg, 0, (size_t)Nn * 4, stream);
  count_edges_kernel<<<(Et + 255) / 256, 256, 0, stream>>>(ei, E, Nn, deg);
  scan_kernel<<<1, 1024, 0, stream>>>(deg, rowptr, cursor, Nn);
  scatter_edges_kernel<<<(Et + 255) / 256, 256, 0, stream>>>(ei, E, Nn, cursor, col);

  // --- layer 1 ---
  {
    dim3 grid((Nn + 127) / 128, 256 / 128);
    sgemm_kernel<128, 128, 16, 2><<<grid, 256, 0, stream>>>(x, W1, xl1, Nn, 256, 128);
  }
  alpha_kernel<<<(Nn * 4 + 255) / 256, 256, 0, stream>>>(xl1, as1, ad1, asrc1, adst1, Nn, 4, 64);
  agg_multi_kernel<<<(Nn + 3) / 4, 256, 0, stream>>>(xl1, asrc1, adst1, rowptr, col, b1, hbuf, Nn);

  // --- layer 2 ---
  {
    dim3 grid((Nn + 127) / 128, 64 / 64);
    sgemm_kernel<128, 64, 32, 1><<<grid, 256, 0, stream>>>(hbuf, W2, xl2, Nn, 64, 256);
  }
  alpha_kernel<<<(Nn + 255) / 256, 256, 0, stream>>>(xl2, as2, ad2, asrc2, adst2, Nn, 1, 64);
  agg_single_kernel<<<(Nn + 3) / 4, 256, 0, stream>>>(xl2, asrc2, adst2, rowptr, col, b2, out, Nn);
}

// Round 3
// 499.915 us; speedup vs baseline: 1.3637x; 1.0836x over previous
//
#include <hip/hip_runtime.h>
#include <math.h>

// ---------------------------------------------------------------------------
// GAT 2-layer (PyG GATConv eval) on gfx950.
// R3: bf16 message payloads (halves gather bytes), deeper gather pipelines,
//     SGEMM reg-prefetch double-buffer. GEMM math stays fp32.
// ---------------------------------------------------------------------------

typedef unsigned short u16;

__device__ __forceinline__ float bflo(unsigned int u) {
  return __builtin_bit_cast(float, u << 16);
}
__device__ __forceinline__ float bfhi(unsigned int u) {
  return __builtin_bit_cast(float, u & 0xffff0000u);
}
__device__ __forceinline__ u16 f2bf(float f) {  // RNE
  unsigned int u = __builtin_bit_cast(unsigned int, f);
  return (u16)((u + 0x7fff + ((u >> 16) & 1)) >> 16);
}

// ---- CSR build ------------------------------------------------------------

__global__ void count_edges_kernel(const int* __restrict__ ei, int E, int Nn,
                                   int* __restrict__ deg) {
  int e = blockIdx.x * blockDim.x + threadIdx.x;
  if (e >= E + Nn) return;
  int dst = (e < E) ? ei[E + e] : (e - E);  // self-loops appended
  atomicAdd(&deg[dst], 1);
}

__global__ void scan_kernel(const int* __restrict__ deg, int* __restrict__ rowptr,
                            int* __restrict__ cursor, int Nn) {
  __shared__ int sums[1024];
  int t = threadIdx.x;
  int chunk = (Nn + 1023) / 1024;
  int lo = min(t * chunk, Nn);
  int hi = min(lo + chunk, Nn);
  int s = 0;
  for (int i = lo; i < hi; ++i) s += deg[i];
  sums[t] = s;
  __syncthreads();
  for (int off = 1; off < 1024; off <<= 1) {
    int v = (t >= off) ? sums[t - off] : 0;
    __syncthreads();
    sums[t] += v;
    __syncthreads();
  }
  int excl = (t == 0) ? 0 : sums[t - 1];
  for (int i = lo; i < hi; ++i) {
    rowptr[i] = excl;
    cursor[i] = excl;
    excl += deg[i];
  }
  if (t == 1023) rowptr[Nn] = sums[1023];
}

__global__ void scatter_edges_kernel(const int* __restrict__ ei, int E, int Nn,
                                     int* __restrict__ cursor, int* __restrict__ col) {
  int e = blockIdx.x * blockDim.x + threadIdx.x;
  if (e >= E + Nn) return;
  int src, dst;
  if (e < E) { src = ei[e]; dst = ei[E + e]; }
  else       { src = dst = e - E; }
  int pos = atomicAdd(&cursor[dst], 1);
  col[pos] = src;
}

// ---- tiled fp32 GEMM, bf16 output: C[MxN] = A[MxK] @ B[KxN] ----------------
// 256 threads; TM=8 (split 4+4 at BM/2), TN=4*TNSPL (split at BN/2 if 2).
// Global->reg prefetch: tile k+1 loads issue before compute on tile k.

template <int BM, int BN, int BK, int TNSPL>
__global__ __launch_bounds__(256) void sgemm_bf16_kernel(
    const float* __restrict__ A, const float* __restrict__ B,
    u16* __restrict__ C, int M, int N, int K) {
  constexpr int TN = 4 * TNSPL;
  constexpr int NTX = BN / TN;        // 16
  constexpr int NTY = 256 / NTX;      // 16
  static_assert(BM / NTY == 8, "TM must be 8");
  constexpr int APASS = BM * BK / 1024;
  constexpr int BPASS = BK * BN / 1024;

  __shared__ float As[BK][BM + 4];    // transposed A tile
  __shared__ float Bs[BK][BN];

  int tid = threadIdx.x;
  int tx = tid % NTX, ty = tid / NTX;
  int bm0 = blockIdx.x * BM, bn0 = blockIdx.y * BN;

  float4 areg[APASS], breg[BPASS];

  auto gload = [&](int k0) {
#pragma unroll
    for (int p = 0; p < APASS; ++p) {
      int lin = p * 1024 + tid * 4;
      int r = lin / BK, c = lin % BK;
      areg[p] = make_float4(0.f, 0.f, 0.f, 0.f);
      if (bm0 + r < M)
        areg[p] = *(const float4*)(A + (size_t)(bm0 + r) * K + k0 + c);
    }
#pragma unroll
    for (int p = 0; p < BPASS; ++p) {
      int lin = p * 1024 + tid * 4;
      int r = lin / BN, c = lin % BN;
      breg[p] = *(const float4*)(B + (size_t)(k0 + r) * N + bn0 + c);
    }
  };
  auto lstore = [&]() {
#pragma unroll
    for (int p = 0; p < APASS; ++p) {
      int lin = p * 1024 + tid * 4;
      int r = lin / BK, c = lin % BK;
      As[c + 0][r] = areg[p].x;
      As[c + 1][r] = areg[p].y;
      As[c + 2][r] = areg[p].z;
      As[c + 3][r] = areg[p].w;
    }
#pragma unroll
    for (int p = 0; p < BPASS; ++p) {
      int lin = p * 1024 + tid * 4;
      int r = lin / BN, c = lin % BN;
      *(float4*)&Bs[r][c] = breg[p];
    }
  };

  float acc[8][TN] = {};
  gload(0);
  for (int k0 = 0; k0 < K; k0 += BK) {
    lstore();
    __syncthreads();
    if (k0 + BK < K) gload(k0 + BK);
#pragma unroll
    for (int k = 0; k < BK; ++k) {
      float a[8], b[TN];
      *(float4*)&a[0] = *(const float4*)&As[k][ty * 4];
      *(float4*)&a[4] = *(const float4*)&As[k][BM / 2 + ty * 4];
      *(float4*)&b[0] = *(const float4*)&Bs[k][tx * 4];
      if constexpr (TNSPL == 2)
        *(float4*)&b[4] = *(const float4*)&Bs[k][BN / 2 + tx * 4];
#pragma unroll
      for (int i = 0; i < 8; ++i)
#pragma unroll
        for (int j = 0; j < TN; ++j)
          acc[i][j] = fmaf(a[i], b[j], acc[i][j]);
    }
    __syncthreads();
  }

#pragma unroll
  for (int i = 0; i < 8; ++i) {
    int row = bm0 + ((i < 4) ? (ty * 4 + i) : (BM / 2 + ty * 4 + i - 4));
    if (row < M) {
      ushort4 o = make_ushort4(f2bf(acc[i][0]), f2bf(acc[i][1]),
                               f2bf(acc[i][2]), f2bf(acc[i][3]));
      *(ushort4*)(C + (size_t)row * N + bn0 + tx * 4) = o;
      if constexpr (TNSPL == 2) {
        ushort4 o2 = make_ushort4(f2bf(acc[i][4]), f2bf(acc[i][5]),
                                  f2bf(acc[i][6]), f2bf(acc[i][7]));
        *(ushort4*)(C + (size_t)row * N + bn0 + BN / 2 + tx * 4) = o2;
      }
    }
  }
}

// ---- per-node attention coefficients (bf16 xl) ------------------------------

__global__ void alpha_kernel(const u16* __restrict__ xlb,
                             const float* __restrict__ a_src,
                             const float* __restrict__ a_dst,
                             float* __restrict__ asrc, float* __restrict__ adst,
                             int NH, int H, int C) {
  int idx = blockIdx.x * blockDim.x + threadIdx.x;  // (n,h)
  if (idx >= NH) return;
  int h = idx % H;
  const u16* row = xlb + (size_t)idx * C;
  float ssum = 0.f, dsum = 0.f;
  for (int c = 0; c < C; c += 8) {
    uint4 v = *(const uint4*)(row + c);
    float f[8] = {bflo(v.x), bfhi(v.x), bflo(v.y), bfhi(v.y),
                  bflo(v.z), bfhi(v.z), bflo(v.w), bfhi(v.w)};
#pragma unroll
    for (int j = 0; j < 8; ++j) {
      ssum = fmaf(f[j], a_src[h * C + c + j], ssum);
      dsum = fmaf(f[j], a_dst[h * C + c + j], dsum);
    }
  }
  asrc[idx] = ssum;
  adst[idx] = dsum;
}

// ---- layer-1 aggregation: H=4, C=64, wave/node, depth-2 pipeline ------------

__global__ void agg_multi_kernel(const u16* __restrict__ xlb,
                                 const float* __restrict__ asrc,
                                 const float* __restrict__ adst,
                                 const int* __restrict__ rowptr,
                                 const int* __restrict__ col,
                                 const float* __restrict__ bias,
                                 float* __restrict__ out, int Nn) {
  int n = blockIdx.x * (blockDim.x >> 6) + (threadIdx.x >> 6);
  if (n >= Nn) return;
  int lane = threadIdx.x & 63;
  int h = lane >> 4;
  float adn = adst[n * 4 + h];
  int beg = rowptr[n], end = rowptr[n + 1];

  float m = -INFINITY, s = 0.f;
  float4 acc = make_float4(0.f, 0.f, 0.f, 0.f);

  float as0 = 0.f, as1 = 0.f;
  uint2 v0 = make_uint2(0, 0), v1 = make_uint2(0, 0);
  {
    int sc = col[beg];
    as0 = asrc[sc * 4 + h];
    v0 = *(const uint2*)(xlb + (size_t)sc * 256 + lane * 4);
    if (beg + 1 < end) {
      int sc1 = col[beg + 1];
      as1 = asrc[sc1 * 4 + h];
      v1 = *(const uint2*)(xlb + (size_t)sc1 * 256 + lane * 4);
    }
  }

  for (int i = beg; i < end; ++i) {
    float e = as0 + adn;
    e = (e > 0.f) ? e : 0.2f * e;            // leaky_relu 0.2
    uint2 vc = v0;
    as0 = as1; v0 = v1;                       // shift pipeline
    if (i + 2 < end) {
      int sc2 = col[i + 2];
      as1 = asrc[sc2 * 4 + h];
      v1 = *(const uint2*)(xlb + (size_t)sc2 * 256 + lane * 4);
    }
    float mn = fmaxf(m, e);
    float r = __expf(m - mn);                 // 0 on first iter (m=-inf)
    float w = __expf(e - mn);
    s = fmaf(s, r, w);
    acc.x = fmaf(acc.x, r, w * bflo(vc.x));
    acc.y = fmaf(acc.y, r, w * bfhi(vc.x));
    acc.z = fmaf(acc.z, r, w * bflo(vc.y));
    acc.w = fmaf(acc.w, r, w * bfhi(vc.y));
    m = mn;
  }
  float inv_s = 1.f / s;

  float4 b = *(const float4*)(bias + lane * 4);
  float4 o;
  o.x = fmaf(acc.x, inv_s, b.x);
  o.y = fmaf(acc.y, inv_s, b.y);
  o.z = fmaf(acc.z, inv_s, b.z);
  o.w = fmaf(acc.w, inv_s, b.w);
  o.x = (o.x > 0.f) ? o.x : __expf(o.x) - 1.f;  // ELU
  o.y = (o.y > 0.f) ? o.y : __expf(o.y) - 1.f;
  o.z = (o.z > 0.f) ? o.z : __expf(o.z) - 1.f;
  o.w = (o.w > 0.f) ? o.w : __expf(o.w) - 1.f;
  *(float4*)(out + (size_t)n * 256 + lane * 4) = o;
}

// ---- layer-2 aggregation: H=1, C=64, wave/node, depth-4 pipeline ------------

__global__ void agg_single_kernel(const u16* __restrict__ xlb,
                                  const float* __restrict__ asrc,
                                  const float* __restrict__ adst,
                                  const int* __restrict__ rowptr,
                                  const int* __restrict__ col,
                                  const float* __restrict__ bias,
                                  float* __restrict__ out, int Nn) {
  int n = blockIdx.x * (blockDim.x >> 6) + (threadIdx.x >> 6);
  if (n >= Nn) return;
  int lane = threadIdx.x & 63;
  float adn = adst[n];
  int beg = rowptr[n], end = rowptr[n + 1];
  int d = end - beg;

  float m = -INFINITY, s = 0.f, acc = 0.f;

  float as0 = 0.f, as1 = 0.f, as2 = 0.f, as3 = 0.f;
  u16 w0 = 0, w1 = 0, w2 = 0, w3 = 0;
  {
    int sc = col[beg];
    as0 = asrc[sc]; w0 = xlb[(size_t)sc * 64 + lane];
    if (d > 1) { sc = col[beg + 1]; as1 = asrc[sc]; w1 = xlb[(size_t)sc * 64 + lane]; }
    if (d > 2) { sc = col[beg + 2]; as2 = asrc[sc]; w2 = xlb[(size_t)sc * 64 + lane]; }
    if (d > 3) { sc = col[beg + 3]; as3 = asrc[sc]; w3 = xlb[(size_t)sc * 64 + lane]; }
  }

  for (int i = beg; i < end; ++i) {
    float e = as0 + adn;
    e = (e > 0.f) ? e : 0.2f * e;
    float vc = bflo((unsigned int)w0);
    as0 = as1; w0 = w1;                       // shift pipeline
    as1 = as2; w1 = w2;
    as2 = as3; w2 = w3;
    if (i + 4 < end) {
      int sc = col[i + 4];
      as3 = asrc[sc];
      w3 = xlb[(size_t)sc * 64 + lane];
    }
    float mn = fmaxf(m, e);
    float r = __expf(m - mn);
    float w = __expf(e - mn);
    s = fmaf(s, r, w);
    acc = fmaf(acc, r, w * vc);
    m = mn;
  }
  out[(size_t)n * 64 + lane] = fmaf(acc, 1.f / s, bias[lane]);
}

// ---------------------------------------------------------------------------

extern "C" void kernel_launch(void* const* d_in, const int* in_sizes, int n_in,
                              void* d_out, int out_size, void* d_ws, size_t ws_size,
                              hipStream_t stream) {
  const float* x   = (const float*)d_in[0];
  const int*   ei  = (const int*)d_in[1];
  const float* W1  = (const float*)d_in[2];
  const float* as1 = (const float*)d_in[3];
  const float* ad1 = (const float*)d_in[4];
  const float* b1  = (const float*)d_in[5];
  const float* W2  = (const float*)d_in[6];
  const float* as2 = (const float*)d_in[7];
  const float* ad2 = (const float*)d_in[8];
  const float* b2  = (const float*)d_in[9];
  float* out = (float*)d_out;

  const int Nn = in_sizes[0] / 128;  // 50000
  const int E  = in_sizes[1] / 2;    // 800000
  const int Et = E + Nn;

  char* base = (char*)d_ws;
  size_t off = 0;
  auto alloc = [&](size_t bytes) -> void* {
    void* p = base + off;
    off = (off + bytes + 255) & ~(size_t)255;
    return p;
  };
  u16*   xlb1   = (u16*)alloc((size_t)Nn * 256 * 2);   // layer1 x@W1, bf16
  float* hbuf   = (float*)alloc((size_t)Nn * 256 * 4); // ELU output, fp32
  float* asrc1  = (float*)alloc((size_t)Nn * 4 * 4);
  float* adst1  = (float*)alloc((size_t)Nn * 4 * 4);
  float* asrc2  = (float*)alloc((size_t)Nn * 4);
  float* adst2  = (float*)alloc((size_t)Nn * 4);
  int*   deg    = (int*)alloc((size_t)Nn * 4);
  int*   rowptr = (int*)alloc((size_t)(Nn + 1) * 4);
  int*   cursor = (int*)alloc((size_t)Nn * 4);
  int*   col    = (int*)alloc((size_t)Et * 4);
  u16*   xlb2   = xlb1;  // layer2 h@W2 bf16, aliases xlb1 (dead after agg1)

  // --- CSR build (shared by both layers) ---
  hipMemsetAsync(deg, 0, (size_t)Nn * 4, stream);
  count_edges_kernel<<<(Et + 255) / 256, 256, 0, stream>>>(ei, E, Nn, deg);
  scan_kernel<<<1, 1024, 0, stream>>>(deg, rowptr, cursor, Nn);
  scatter_edges_kernel<<<(Et + 255) / 256, 256, 0, stream>>>(ei, E, Nn, cursor, col);

  // --- layer 1 ---
  {
    dim3 grid((Nn + 127) / 128, 2);
    sgemm_bf16_kernel<128, 128, 16, 2><<<grid, 256, 0, stream>>>(x, W1, xlb1, Nn, 256, 128);
  }
  alpha_kernel<<<(Nn * 4 + 255) / 256, 256, 0, stream>>>(xlb1, as1, ad1, asrc1, adst1, Nn * 4, 4, 64);
  agg_multi_kernel<<<(Nn + 3) / 4, 256, 0, stream>>>(xlb1, asrc1, adst1, rowptr, col, b1, hbuf, Nn);

  // --- layer 2 ---
  {
    dim3 grid((Nn + 127) / 128, 1);
    sgemm_bf16_kernel<128, 64, 32, 1><<<grid, 256, 0, stream>>>(hbuf, W2, xlb2, Nn, 64, 256);
  }
  alpha_kernel<<<(Nn + 255) / 256, 256, 0, stream>>>(xlb2, as2, ad2, asrc2, adst2, Nn, 1, 64);
  agg_single_kernel<<<(Nn + 3) / 4, 256, 0, stream>>>(xlb2, asrc2, adst2, rowptr, col, b2, out, Nn);
}

// Round 4
// 402.250 us; speedup vs baseline: 1.6948x; 1.2428x over previous
//
#include <hip/hip_runtime.h>
#include <math.h>

// ---------------------------------------------------------------------------
// GAT 2-layer (PyG GATConv eval) on gfx950.
// R4: replace 110us single-block scan with 3-kernel two-level parallel scan.
//     (R3: bf16 message payloads, pipelined gathers, reg-prefetch SGEMM.)
// ---------------------------------------------------------------------------

typedef unsigned short u16;

__device__ __forceinline__ float bflo(unsigned int u) {
  return __builtin_bit_cast(float, u << 16);
}
__device__ __forceinline__ float bfhi(unsigned int u) {
  return __builtin_bit_cast(float, u & 0xffff0000u);
}
__device__ __forceinline__ u16 f2bf(float f) {  // RNE
  unsigned int u = __builtin_bit_cast(unsigned int, f);
  return (u16)((u + 0x7fff + ((u >> 16) & 1)) >> 16);
}

// ---- CSR build ------------------------------------------------------------

__global__ void count_edges_kernel(const int* __restrict__ ei, int E, int Nn,
                                   int* __restrict__ deg) {
  int e = blockIdx.x * blockDim.x + threadIdx.x;
  if (e >= E + Nn) return;
  int dst = (e < E) ? ei[E + e] : (e - E);  // self-loops appended
  atomicAdd(&deg[dst], 1);
}

// Two-level scan over Ntot = Nn+1 entries (deg[Nn] is zero -> rowptr[Nn]=total).
// Level 1: per-block (1024 elems) reduction -> partials.
__global__ void scan_partials_kernel(const int* __restrict__ deg,
                                     int* __restrict__ partials, int Ntot) {
  __shared__ int red[256];
  int t = threadIdx.x;
  int base = blockIdx.x * 1024 + t * 4;
  int s = 0;
  if (base + 3 < Ntot) {
    int4 v = *(const int4*)(deg + base);
    s = v.x + v.y + v.z + v.w;
  } else {
    for (int i = 0; i < 4; ++i)
      if (base + i < Ntot) s += deg[base + i];
  }
  red[t] = s;
  __syncthreads();
  for (int off = 128; off > 0; off >>= 1) {
    if (t < off) red[t] += red[t + off];
    __syncthreads();
  }
  if (t == 0) partials[blockIdx.x] = red[0];
}

// Level 2: exclusive scan of <=256 partials, single block.
__global__ void scan_top_kernel(int* __restrict__ partials, int NB) {
  __shared__ int sh[256];
  int t = threadIdx.x;
  sh[t] = (t < NB) ? partials[t] : 0;
  __syncthreads();
  for (int off = 1; off < 256; off <<= 1) {
    int v = (t >= off) ? sh[t - off] : 0;
    __syncthreads();
    sh[t] += v;
    __syncthreads();
  }
  if (t < NB) partials[t] = (t == 0) ? 0 : sh[t - 1];
}

// Level 3: per-block local scan + block offset -> rowptr, cursor.
__global__ void scan_final_kernel(const int* __restrict__ deg,
                                  const int* __restrict__ partials,
                                  int* __restrict__ rowptr,
                                  int* __restrict__ cursor, int Ntot) {
  __shared__ int sums[256];
  int t = threadIdx.x;
  int base = blockIdx.x * 1024 + t * 4;
  int4 v = make_int4(0, 0, 0, 0);
  if (base + 3 < Ntot) {
    v = *(const int4*)(deg + base);
  } else {
    if (base + 0 < Ntot) v.x = deg[base + 0];
    if (base + 1 < Ntot) v.y = deg[base + 1];
    if (base + 2 < Ntot) v.z = deg[base + 2];
    if (base + 3 < Ntot) v.w = deg[base + 3];
  }
  sums[t] = v.x + v.y + v.z + v.w;
  __syncthreads();
  for (int off = 1; off < 256; off <<= 1) {
    int u = (t >= off) ? sums[t - off] : 0;
    __syncthreads();
    sums[t] += u;
    __syncthreads();
  }
  int excl = partials[blockIdx.x] + ((t == 0) ? 0 : sums[t - 1]);
  int4 r;
  r.x = excl;
  r.y = r.x + v.x;
  r.z = r.y + v.y;
  r.w = r.z + v.z;
  if (base + 3 < Ntot) {
    *(int4*)(rowptr + base) = r;
    *(int4*)(cursor + base) = r;
  } else {
    if (base + 0 < Ntot) { rowptr[base + 0] = r.x; cursor[base + 0] = r.x; }
    if (base + 1 < Ntot) { rowptr[base + 1] = r.y; cursor[base + 1] = r.y; }
    if (base + 2 < Ntot) { rowptr[base + 2] = r.z; cursor[base + 2] = r.z; }
    if (base + 3 < Ntot) { rowptr[base + 3] = r.w; cursor[base + 3] = r.w; }
  }
}

__global__ void scatter_edges_kernel(const int* __restrict__ ei, int E, int Nn,
                                     int* __restrict__ cursor, int* __restrict__ col) {
  int e = blockIdx.x * blockDim.x + threadIdx.x;
  if (e >= E + Nn) return;
  int src, dst;
  if (e < E) { src = ei[e]; dst = ei[E + e]; }
  else       { src = dst = e - E; }
  int pos = atomicAdd(&cursor[dst], 1);
  col[pos] = src;
}

// ---- tiled fp32 GEMM, bf16 output: C[MxN] = A[MxK] @ B[KxN] ----------------

template <int BM, int BN, int BK, int TNSPL>
__global__ __launch_bounds__(256) void sgemm_bf16_kernel(
    const float* __restrict__ A, const float* __restrict__ B,
    u16* __restrict__ C, int M, int N, int K) {
  constexpr int TN = 4 * TNSPL;
  constexpr int NTX = BN / TN;        // 16
  constexpr int NTY = 256 / NTX;      // 16
  static_assert(BM / NTY == 8, "TM must be 8");
  constexpr int APASS = BM * BK / 1024;
  constexpr int BPASS = BK * BN / 1024;

  __shared__ float As[BK][BM + 4];    // transposed A tile
  __shared__ float Bs[BK][BN];

  int tid = threadIdx.x;
  int tx = tid % NTX, ty = tid / NTX;
  int bm0 = blockIdx.x * BM, bn0 = blockIdx.y * BN;

  float4 areg[APASS], breg[BPASS];

  auto gload = [&](int k0) {
#pragma unroll
    for (int p = 0; p < APASS; ++p) {
      int lin = p * 1024 + tid * 4;
      int r = lin / BK, c = lin % BK;
      areg[p] = make_float4(0.f, 0.f, 0.f, 0.f);
      if (bm0 + r < M)
        areg[p] = *(const float4*)(A + (size_t)(bm0 + r) * K + k0 + c);
    }
#pragma unroll
    for (int p = 0; p < BPASS; ++p) {
      int lin = p * 1024 + tid * 4;
      int r = lin / BN, c = lin % BN;
      breg[p] = *(const float4*)(B + (size_t)(k0 + r) * N + bn0 + c);
    }
  };
  auto lstore = [&]() {
#pragma unroll
    for (int p = 0; p < APASS; ++p) {
      int lin = p * 1024 + tid * 4;
      int r = lin / BK, c = lin % BK;
      As[c + 0][r] = areg[p].x;
      As[c + 1][r] = areg[p].y;
      As[c + 2][r] = areg[p].z;
      As[c + 3][r] = areg[p].w;
    }
#pragma unroll
    for (int p = 0; p < BPASS; ++p) {
      int lin = p * 1024 + tid * 4;
      int r = lin / BN, c = lin % BN;
      *(float4*)&Bs[r][c] = breg[p];
    }
  };

  float acc[8][TN] = {};
  gload(0);
  for (int k0 = 0; k0 < K; k0 += BK) {
    lstore();
    __syncthreads();
    if (k0 + BK < K) gload(k0 + BK);
#pragma unroll
    for (int k = 0; k < BK; ++k) {
      float a[8], b[TN];
      *(float4*)&a[0] = *(const float4*)&As[k][ty * 4];
      *(float4*)&a[4] = *(const float4*)&As[k][BM / 2 + ty * 4];
      *(float4*)&b[0] = *(const float4*)&Bs[k][tx * 4];
      if constexpr (TNSPL == 2)
        *(float4*)&b[4] = *(const float4*)&Bs[k][BN / 2 + tx * 4];
#pragma unroll
      for (int i = 0; i < 8; ++i)
#pragma unroll
        for (int j = 0; j < TN; ++j)
          acc[i][j] = fmaf(a[i], b[j], acc[i][j]);
    }
    __syncthreads();
  }

#pragma unroll
  for (int i = 0; i < 8; ++i) {
    int row = bm0 + ((i < 4) ? (ty * 4 + i) : (BM / 2 + ty * 4 + i - 4));
    if (row < M) {
      ushort4 o = make_ushort4(f2bf(acc[i][0]), f2bf(acc[i][1]),
                               f2bf(acc[i][2]), f2bf(acc[i][3]));
      *(ushort4*)(C + (size_t)row * N + bn0 + tx * 4) = o;
      if constexpr (TNSPL == 2) {
        ushort4 o2 = make_ushort4(f2bf(acc[i][4]), f2bf(acc[i][5]),
                                  f2bf(acc[i][6]), f2bf(acc[i][7]));
        *(ushort4*)(C + (size_t)row * N + bn0 + BN / 2 + tx * 4) = o2;
      }
    }
  }
}

// ---- per-node attention coefficients (bf16 xl) ------------------------------

__global__ void alpha_kernel(const u16* __restrict__ xlb,
                             const float* __restrict__ a_src,
                             const float* __restrict__ a_dst,
                             float* __restrict__ asrc, float* __restrict__ adst,
                             int NH, int H, int C) {
  int idx = blockIdx.x * blockDim.x + threadIdx.x;  // (n,h)
  if (idx >= NH) return;
  int h = idx % H;
  const u16* row = xlb + (size_t)idx * C;
  float ssum = 0.f, dsum = 0.f;
  for (int c = 0; c < C; c += 8) {
    uint4 v = *(const uint4*)(row + c);
    float f[8] = {bflo(v.x), bfhi(v.x), bflo(v.y), bfhi(v.y),
                  bflo(v.z), bfhi(v.z), bflo(v.w), bfhi(v.w)};
#pragma unroll
    for (int j = 0; j < 8; ++j) {
      ssum = fmaf(f[j], a_src[h * C + c + j], ssum);
      dsum = fmaf(f[j], a_dst[h * C + c + j], dsum);
    }
  }
  asrc[idx] = ssum;
  adst[idx] = dsum;
}

// ---- layer-1 aggregation: H=4, C=64, wave/node, depth-2 pipeline ------------

__global__ void agg_multi_kernel(const u16* __restrict__ xlb,
                                 const float* __restrict__ asrc,
                                 const float* __restrict__ adst,
                                 const int* __restrict__ rowptr,
                                 const int* __restrict__ col,
                                 const float* __restrict__ bias,
                                 float* __restrict__ out, int Nn) {
  int n = blockIdx.x * (blockDim.x >> 6) + (threadIdx.x >> 6);
  if (n >= Nn) return;
  int lane = threadIdx.x & 63;
  int h = lane >> 4;
  float adn = adst[n * 4 + h];
  int beg = rowptr[n], end = rowptr[n + 1];

  float m = -INFINITY, s = 0.f;
  float4 acc = make_float4(0.f, 0.f, 0.f, 0.f);

  float as0 = 0.f, as1 = 0.f;
  uint2 v0 = make_uint2(0, 0), v1 = make_uint2(0, 0);
  {
    int sc = col[beg];
    as0 = asrc[sc * 4 + h];
    v0 = *(const uint2*)(xlb + (size_t)sc * 256 + lane * 4);
    if (beg + 1 < end) {
      int sc1 = col[beg + 1];
      as1 = asrc[sc1 * 4 + h];
      v1 = *(const uint2*)(xlb + (size_t)sc1 * 256 + lane * 4);
    }
  }

  for (int i = beg; i < end; ++i) {
    float e = as0 + adn;
    e = (e > 0.f) ? e : 0.2f * e;            // leaky_relu 0.2
    uint2 vc = v0;
    as0 = as1; v0 = v1;                       // shift pipeline
    if (i + 2 < end) {
      int sc2 = col[i + 2];
      as1 = asrc[sc2 * 4 + h];
      v1 = *(const uint2*)(xlb + (size_t)sc2 * 256 + lane * 4);
    }
    float mn = fmaxf(m, e);
    float r = __expf(m - mn);                 // 0 on first iter (m=-inf)
    float w = __expf(e - mn);
    s = fmaf(s, r, w);
    acc.x = fmaf(acc.x, r, w * bflo(vc.x));
    acc.y = fmaf(acc.y, r, w * bfhi(vc.x));
    acc.z = fmaf(acc.z, r, w * bflo(vc.y));
    acc.w = fmaf(acc.w, r, w * bfhi(vc.y));
    m = mn;
  }
  float inv_s = 1.f / s;

  float4 b = *(const float4*)(bias + lane * 4);
  float4 o;
  o.x = fmaf(acc.x, inv_s, b.x);
  o.y = fmaf(acc.y, inv_s, b.y);
  o.z = fmaf(acc.z, inv_s, b.z);
  o.w = fmaf(acc.w, inv_s, b.w);
  o.x = (o.x > 0.f) ? o.x : __expf(o.x) - 1.f;  // ELU
  o.y = (o.y > 0.f) ? o.y : __expf(o.y) - 1.f;
  o.z = (o.z > 0.f) ? o.z : __expf(o.z) - 1.f;
  o.w = (o.w > 0.f) ? o.w : __expf(o.w) - 1.f;
  *(float4*)(out + (size_t)n * 256 + lane * 4) = o;
}

// ---- layer-2 aggregation: H=1, C=64, wave/node, depth-4 pipeline ------------

__global__ void agg_single_kernel(const u16* __restrict__ xlb,
                                  const float* __restrict__ asrc,
                                  const float* __restrict__ adst,
                                  const int* __restrict__ rowptr,
                                  const int* __restrict__ col,
                                  const float* __restrict__ bias,
                                  float* __restrict__ out, int Nn) {
  int n = blockIdx.x * (blockDim.x >> 6) + (threadIdx.x >> 6);
  if (n >= Nn) return;
  int lane = threadIdx.x & 63;
  float adn = adst[n];
  int beg = rowptr[n], end = rowptr[n + 1];
  int d = end - beg;

  float m = -INFINITY, s = 0.f, acc = 0.f;

  float as0 = 0.f, as1 = 0.f, as2 = 0.f, as3 = 0.f;
  u16 w0 = 0, w1 = 0, w2 = 0, w3 = 0;
  {
    int sc = col[beg];
    as0 = asrc[sc]; w0 = xlb[(size_t)sc * 64 + lane];
    if (d > 1) { sc = col[beg + 1]; as1 = asrc[sc]; w1 = xlb[(size_t)sc * 64 + lane]; }
    if (d > 2) { sc = col[beg + 2]; as2 = asrc[sc]; w2 = xlb[(size_t)sc * 64 + lane]; }
    if (d > 3) { sc = col[beg + 3]; as3 = asrc[sc]; w3 = xlb[(size_t)sc * 64 + lane]; }
  }

  for (int i = beg; i < end; ++i) {
    float e = as0 + adn;
    e = (e > 0.f) ? e : 0.2f * e;
    float vc = bflo((unsigned int)w0);
    as0 = as1; w0 = w1;                       // shift pipeline
    as1 = as2; w1 = w2;
    as2 = as3; w2 = w3;
    if (i + 4 < end) {
      int sc = col[i + 4];
      as3 = asrc[sc];
      w3 = xlb[(size_t)sc * 64 + lane];
    }
    float mn = fmaxf(m, e);
    float r = __expf(m - mn);
    float w = __expf(e - mn);
    s = fmaf(s, r, w);
    acc = fmaf(acc, r, w * vc);
    m = mn;
  }
  out[(size_t)n * 64 + lane] = fmaf(acc, 1.f / s, bias[lane]);
}

// ---------------------------------------------------------------------------

extern "C" void kernel_launch(void* const* d_in, const int* in_sizes, int n_in,
                              void* d_out, int out_size, void* d_ws, size_t ws_size,
                              hipStream_t stream) {
  const float* x   = (const float*)d_in[0];
  const int*   ei  = (const int*)d_in[1];
  const float* W1  = (const float*)d_in[2];
  const float* as1 = (const float*)d_in[3];
  const float* ad1 = (const float*)d_in[4];
  const float* b1  = (const float*)d_in[5];
  const float* W2  = (const float*)d_in[6];
  const float* as2 = (const float*)d_in[7];
  const float* ad2 = (const float*)d_in[8];
  const float* b2  = (const float*)d_in[9];
  float* out = (float*)d_out;

  const int Nn = in_sizes[0] / 128;  // 50000
  const int E  = in_sizes[1] / 2;    // 800000
  const int Et = E + Nn;
  const int Ntot = Nn + 1;           // scan domain (virtual deg[Nn]=0)
  const int NB = (Ntot + 1023) / 1024;

  char* base = (char*)d_ws;
  size_t off = 0;
  auto alloc = [&](size_t bytes) -> void* {
    void* p = base + off;
    off = (off + bytes + 255) & ~(size_t)255;
    return p;
  };
  u16*   xlb1     = (u16*)alloc((size_t)Nn * 256 * 2);   // layer1 x@W1, bf16
  float* hbuf     = (float*)alloc((size_t)Nn * 256 * 4); // ELU output, fp32
  float* asrc1    = (float*)alloc((size_t)Nn * 4 * 4);
  float* adst1    = (float*)alloc((size_t)Nn * 4 * 4);
  float* asrc2    = (float*)alloc((size_t)Nn * 4);
  float* adst2    = (float*)alloc((size_t)Nn * 4);
  int*   deg      = (int*)alloc((size_t)(Ntot + 8) * 4);
  int*   rowptr   = (int*)alloc((size_t)(Ntot + 8) * 4);
  int*   cursor   = (int*)alloc((size_t)(Ntot + 8) * 4);
  int*   partials = (int*)alloc(256 * 4);
  int*   col      = (int*)alloc((size_t)Et * 4);
  u16*   xlb2     = xlb1;  // layer2 h@W2 bf16, aliases xlb1 (dead after agg1)

  // --- CSR build (shared by both layers) ---
  hipMemsetAsync(deg, 0, (size_t)Ntot * 4, stream);
  count_edges_kernel<<<(Et + 255) / 256, 256, 0, stream>>>(ei, E, Nn, deg);
  scan_partials_kernel<<<NB, 256, 0, stream>>>(deg, partials, Ntot);
  scan_top_kernel<<<1, 256, 0, stream>>>(partials, NB);
  scan_final_kernel<<<NB, 256, 0, stream>>>(deg, partials, rowptr, cursor, Ntot);
  scatter_edges_kernel<<<(Et + 255) / 256, 256, 0, stream>>>(ei, E, Nn, cursor, col);

  // --- layer 1 ---
  {
    dim3 grid((Nn + 127) / 128, 2);
    sgemm_bf16_kernel<128, 128, 16, 2><<<grid, 256, 0, stream>>>(x, W1, xlb1, Nn, 256, 128);
  }
  alpha_kernel<<<(Nn * 4 + 255) / 256, 256, 0, stream>>>(xlb1, as1, ad1, asrc1, adst1, Nn * 4, 4, 64);
  agg_multi_kernel<<<(Nn + 3) / 4, 256, 0, stream>>>(xlb1, asrc1, adst1, rowptr, col, b1, hbuf, Nn);

  // --- layer 2 ---
  {
    dim3 grid((Nn + 127) / 128, 1);
    sgemm_bf16_kernel<128, 64, 32, 1><<<grid, 256, 0, stream>>>(hbuf, W2, xlb2, Nn, 64, 256);
  }
  alpha_kernel<<<(Nn + 255) / 256, 256, 0, stream>>>(xlb2, as2, ad2, asrc2, adst2, Nn, 1, 64);
  agg_single_kernel<<<(Nn + 3) / 4, 256, 0, stream>>>(xlb2, asrc2, adst2, rowptr, col, b2, out, Nn);
}

// Round 5
// 335.333 us; speedup vs baseline: 2.0331x; 1.1996x over previous
//
#include <hip/hip_runtime.h>
#include <math.h>

// ---------------------------------------------------------------------------
// GAT 2-layer (PyG GATConv eval) on gfx950.
// R5: both GEMMs -> MFMA bf16 (16x16x32), x/W pre-cast+transpose to bf16,
//     h buffer stored bf16 (feeds GEMM2 directly).
// R4: two-level parallel scan. R3: bf16 payload gathers.
// ---------------------------------------------------------------------------

typedef unsigned short u16;
typedef short s8v __attribute__((ext_vector_type(8)));    // 8 bf16 (4 VGPR)
typedef float f32x4 __attribute__((ext_vector_type(4)));  // MFMA acc

__device__ __forceinline__ float bflo(unsigned int u) {
  return __builtin_bit_cast(float, u << 16);
}
__device__ __forceinline__ float bfhi(unsigned int u) {
  return __builtin_bit_cast(float, u & 0xffff0000u);
}
__device__ __forceinline__ u16 f2bf(float f) {  // RNE
  unsigned int u = __builtin_bit_cast(unsigned int, f);
  return (u16)((u + 0x7fff + ((u >> 16) & 1)) >> 16);
}

// ---- CSR build ------------------------------------------------------------

__global__ void count_edges_kernel(const int* __restrict__ ei, int E, int Nn,
                                   int* __restrict__ deg) {
  int e = blockIdx.x * blockDim.x + threadIdx.x;
  if (e >= E + Nn) return;
  int dst = (e < E) ? ei[E + e] : (e - E);  // self-loops appended
  atomicAdd(&deg[dst], 1);
}

__global__ void scan_partials_kernel(const int* __restrict__ deg,
                                     int* __restrict__ partials, int Ntot) {
  __shared__ int red[256];
  int t = threadIdx.x;
  int base = blockIdx.x * 1024 + t * 4;
  int s = 0;
  if (base + 3 < Ntot) {
    int4 v = *(const int4*)(deg + base);
    s = v.x + v.y + v.z + v.w;
  } else {
    for (int i = 0; i < 4; ++i)
      if (base + i < Ntot) s += deg[base + i];
  }
  red[t] = s;
  __syncthreads();
  for (int off = 128; off > 0; off >>= 1) {
    if (t < off) red[t] += red[t + off];
    __syncthreads();
  }
  if (t == 0) partials[blockIdx.x] = red[0];
}

__global__ void scan_top_kernel(int* __restrict__ partials, int NB) {
  __shared__ int sh[256];
  int t = threadIdx.x;
  sh[t] = (t < NB) ? partials[t] : 0;
  __syncthreads();
  for (int off = 1; off < 256; off <<= 1) {
    int v = (t >= off) ? sh[t - off] : 0;
    __syncthreads();
    sh[t] += v;
    __syncthreads();
  }
  if (t < NB) partials[t] = (t == 0) ? 0 : sh[t - 1];
}

__global__ void scan_final_kernel(const int* __restrict__ deg,
                                  const int* __restrict__ partials,
                                  int* __restrict__ rowptr,
                                  int* __restrict__ cursor, int Ntot) {
  __shared__ int sums[256];
  int t = threadIdx.x;
  int base = blockIdx.x * 1024 + t * 4;
  int4 v = make_int4(0, 0, 0, 0);
  if (base + 3 < Ntot) {
    v = *(const int4*)(deg + base);
  } else {
    if (base + 0 < Ntot) v.x = deg[base + 0];
    if (base + 1 < Ntot) v.y = deg[base + 1];
    if (base + 2 < Ntot) v.z = deg[base + 2];
    if (base + 3 < Ntot) v.w = deg[base + 3];
  }
  sums[t] = v.x + v.y + v.z + v.w;
  __syncthreads();
  for (int off = 1; off < 256; off <<= 1) {
    int u = (t >= off) ? sums[t - off] : 0;
    __syncthreads();
    sums[t] += u;
    __syncthreads();
  }
  int excl = partials[blockIdx.x] + ((t == 0) ? 0 : sums[t - 1]);
  int4 r;
  r.x = excl;
  r.y = r.x + v.x;
  r.z = r.y + v.y;
  r.w = r.z + v.z;
  if (base + 3 < Ntot) {
    *(int4*)(rowptr + base) = r;
    *(int4*)(cursor + base) = r;
  } else {
    if (base + 0 < Ntot) { rowptr[base + 0] = r.x; cursor[base + 0] = r.x; }
    if (base + 1 < Ntot) { rowptr[base + 1] = r.y; cursor[base + 1] = r.y; }
    if (base + 2 < Ntot) { rowptr[base + 2] = r.z; cursor[base + 2] = r.z; }
    if (base + 3 < Ntot) { rowptr[base + 3] = r.w; cursor[base + 3] = r.w; }
  }
}

__global__ void scatter_edges_kernel(const int* __restrict__ ei, int E, int Nn,
                                     int* __restrict__ cursor, int* __restrict__ col) {
  int e = blockIdx.x * blockDim.x + threadIdx.x;
  if (e >= E + Nn) return;
  int src, dst;
  if (e < E) { src = ei[e]; dst = ei[E + e]; }
  else       { src = dst = e - E; }
  int pos = atomicAdd(&cursor[dst], 1);
  col[pos] = src;
}

// ---- prep: cast x -> bf16; transpose W1, W2 -> [N][K] bf16 ------------------

__global__ void cast_prep_kernel(const float* __restrict__ x, u16* __restrict__ xb,
                                 int nx4,
                                 const float* __restrict__ W1, u16* __restrict__ W1T,
                                 int K1, int N1,
                                 const float* __restrict__ W2, u16* __restrict__ W2T,
                                 int K2, int N2) {
  int i = blockIdx.x * blockDim.x + threadIdx.x;
  if (i < nx4) {
    float4 v = *(const float4*)(x + (size_t)i * 4);
    ushort4 o = make_ushort4(f2bf(v.x), f2bf(v.y), f2bf(v.z), f2bf(v.w));
    *(ushort4*)(xb + (size_t)i * 4) = o;
    return;
  }
  int e = i - nx4;
  int tot1 = K1 * N1;
  if (e < tot1) {
    int k = e / N1, n = e % N1;
    W1T[n * K1 + k] = f2bf(W1[e]);
    return;
  }
  e -= tot1;
  if (e < K2 * N2) {
    int k = e / N2, n = e % N2;
    W2T[n * K2 + k] = f2bf(W2[e]);
  }
}

// ---- MFMA bf16 GEMM: C[M][NC](bf16) = A[Mpad][K](bf16) @ Bt[N][K](bf16)^T ---
// BM=128, BK=32, 256 threads = 4 waves (2x2). Wave tile 64 x (BN/2).
// Frag reads: one ds_read_b128 per fragment; PADK=40 -> 80B row stride
// (2-way bank aliasing, free). C/D layout per m89: col=lane&15,
// row=(lane>>4)*4+reg.

template <int BN>
__global__ __launch_bounds__(256) void gemm_mfma_kernel(
    const u16* __restrict__ A, const u16* __restrict__ Bt,
    u16* __restrict__ C, int M, int K, int NC) {
  constexpr int BM = 128, BK = 32, PK = 40;
  constexpr int NJ = BN / 32;  // frags per wave in N (BN=128 -> 4, 64 -> 2)
  __shared__ short As[BM][PK];
  __shared__ short Bs[BN][PK];

  int tid = threadIdx.x;
  int lane = tid & 63, w = tid >> 6;
  int wm = (w >> 1) * 64, wn = (w & 1) * (BN / 2);
  int bm0 = blockIdx.x * BM, bn0 = blockIdx.y * BN;
  int fr = lane & 15, fk = (lane >> 4) * 8;

  f32x4 acc[4][NJ] = {};

  for (int k0 = 0; k0 < K; k0 += BK) {
#pragma unroll
    for (int p = 0; p < BM * BK / 2048; ++p) {
      int idx = p * 2048 + tid * 8;
      int r = idx / BK, c = idx % BK;
      *(s8v*)&As[r][c] = *(const s8v*)(A + (size_t)(bm0 + r) * K + k0 + c);
    }
#pragma unroll
    for (int p = 0; p < BN * BK / 2048; ++p) {
      int idx = p * 2048 + tid * 8;
      int r = idx / BK, c = idx % BK;
      *(s8v*)&Bs[r][c] = *(const s8v*)(Bt + (size_t)(bn0 + r) * K + k0 + c);
    }
    __syncthreads();

    s8v af[4], bf[NJ];
#pragma unroll
    for (int i = 0; i < 4; ++i)
      af[i] = *(const s8v*)&As[wm + i * 16 + fr][fk];
#pragma unroll
    for (int j = 0; j < NJ; ++j)
      bf[j] = *(const s8v*)&Bs[wn + j * 16 + fr][fk];
#pragma unroll
    for (int i = 0; i < 4; ++i)
#pragma unroll
      for (int j = 0; j < NJ; ++j)
        acc[i][j] = __builtin_amdgcn_mfma_f32_16x16x32_bf16(af[i], bf[j], acc[i][j], 0, 0, 0);
    __syncthreads();
  }

#pragma unroll
  for (int i = 0; i < 4; ++i)
#pragma unroll
    for (int j = 0; j < NJ; ++j)
#pragma unroll
      for (int r = 0; r < 4; ++r) {
        int row = bm0 + wm + i * 16 + (lane >> 4) * 4 + r;
        if (row < M)
          C[(size_t)row * NC + bn0 + wn + j * 16 + fr] = f2bf(acc[i][j][r]);
      }
}

// ---- per-node attention coefficients (bf16 xl) ------------------------------

__global__ void alpha_kernel(const u16* __restrict__ xlb,
                             const float* __restrict__ a_src,
                             const float* __restrict__ a_dst,
                             float* __restrict__ asrc, float* __restrict__ adst,
                             int NH, int H, int C) {
  int idx = blockIdx.x * blockDim.x + threadIdx.x;  // (n,h)
  if (idx >= NH) return;
  int h = idx % H;
  const u16* row = xlb + (size_t)idx * C;
  float ssum = 0.f, dsum = 0.f;
  for (int c = 0; c < C; c += 8) {
    uint4 v = *(const uint4*)(row + c);
    float f[8] = {bflo(v.x), bfhi(v.x), bflo(v.y), bfhi(v.y),
                  bflo(v.z), bfhi(v.z), bflo(v.w), bfhi(v.w)};
#pragma unroll
    for (int j = 0; j < 8; ++j) {
      ssum = fmaf(f[j], a_src[h * C + c + j], ssum);
      dsum = fmaf(f[j], a_dst[h * C + c + j], dsum);
    }
  }
  asrc[idx] = ssum;
  adst[idx] = dsum;
}

// ---- layer-1 aggregation: H=4, C=64, wave/node, depth-2 pipeline ------------
// epilogue: +bias, ELU, write h as bf16 (feeds GEMM2)

__global__ void agg_multi_kernel(const u16* __restrict__ xlb,
                                 const float* __restrict__ asrc,
                                 const float* __restrict__ adst,
                                 const int* __restrict__ rowptr,
                                 const int* __restrict__ col,
                                 const float* __restrict__ bias,
                                 u16* __restrict__ hb, int Nn) {
  int n = blockIdx.x * (blockDim.x >> 6) + (threadIdx.x >> 6);
  if (n >= Nn) return;
  int lane = threadIdx.x & 63;
  int h = lane >> 4;
  float adn = adst[n * 4 + h];
  int beg = rowptr[n], end = rowptr[n + 1];

  float m = -INFINITY, s = 0.f;
  float4 acc = make_float4(0.f, 0.f, 0.f, 0.f);

  float as0 = 0.f, as1 = 0.f;
  uint2 v0 = make_uint2(0, 0), v1 = make_uint2(0, 0);
  {
    int sc = col[beg];
    as0 = asrc[sc * 4 + h];
    v0 = *(const uint2*)(xlb + (size_t)sc * 256 + lane * 4);
    if (beg + 1 < end) {
      int sc1 = col[beg + 1];
      as1 = asrc[sc1 * 4 + h];
      v1 = *(const uint2*)(xlb + (size_t)sc1 * 256 + lane * 4);
    }
  }

  for (int i = beg; i < end; ++i) {
    float e = as0 + adn;
    e = (e > 0.f) ? e : 0.2f * e;            // leaky_relu 0.2
    uint2 vc = v0;
    as0 = as1; v0 = v1;                       // shift pipeline
    if (i + 2 < end) {
      int sc2 = col[i + 2];
      as1 = asrc[sc2 * 4 + h];
      v1 = *(const uint2*)(xlb + (size_t)sc2 * 256 + lane * 4);
    }
    float mn = fmaxf(m, e);
    float r = __expf(m - mn);                 // 0 on first iter (m=-inf)
    float w = __expf(e - mn);
    s = fmaf(s, r, w);
    acc.x = fmaf(acc.x, r, w * bflo(vc.x));
    acc.y = fmaf(acc.y, r, w * bfhi(vc.x));
    acc.z = fmaf(acc.z, r, w * bflo(vc.y));
    acc.w = fmaf(acc.w, r, w * bfhi(vc.y));
    m = mn;
  }
  float inv_s = 1.f / s;

  float4 b = *(const float4*)(bias + lane * 4);
  float4 o;
  o.x = fmaf(acc.x, inv_s, b.x);
  o.y = fmaf(acc.y, inv_s, b.y);
  o.z = fmaf(acc.z, inv_s, b.z);
  o.w = fmaf(acc.w, inv_s, b.w);
  o.x = (o.x > 0.f) ? o.x : __expf(o.x) - 1.f;  // ELU
  o.y = (o.y > 0.f) ? o.y : __expf(o.y) - 1.f;
  o.z = (o.z > 0.f) ? o.z : __expf(o.z) - 1.f;
  o.w = (o.w > 0.f) ? o.w : __expf(o.w) - 1.f;
  ushort4 ov = make_ushort4(f2bf(o.x), f2bf(o.y), f2bf(o.z), f2bf(o.w));
  *(ushort4*)(hb + (size_t)n * 256 + lane * 4) = ov;
}

// ---- layer-2 aggregation: H=1, C=64, wave/node, depth-4 pipeline ------------

__global__ void agg_single_kernel(const u16* __restrict__ xlb,
                                  const float* __restrict__ asrc,
                                  const float* __restrict__ adst,
                                  const int* __restrict__ rowptr,
                                  const int* __restrict__ col,
                                  const float* __restrict__ bias,
                                  float* __restrict__ out, int Nn) {
  int n = blockIdx.x * (blockDim.x >> 6) + (threadIdx.x >> 6);
  if (n >= Nn) return;
  int lane = threadIdx.x & 63;
  float adn = adst[n];
  int beg = rowptr[n], end = rowptr[n + 1];
  int d = end - beg;

  float m = -INFINITY, s = 0.f, acc = 0.f;

  float as0 = 0.f, as1 = 0.f, as2 = 0.f, as3 = 0.f;
  u16 w0 = 0, w1 = 0, w2 = 0, w3 = 0;
  {
    int sc = col[beg];
    as0 = asrc[sc]; w0 = xlb[(size_t)sc * 64 + lane];
    if (d > 1) { sc = col[beg + 1]; as1 = asrc[sc]; w1 = xlb[(size_t)sc * 64 + lane]; }
    if (d > 2) { sc = col[beg + 2]; as2 = asrc[sc]; w2 = xlb[(size_t)sc * 64 + lane]; }
    if (d > 3) { sc = col[beg + 3]; as3 = asrc[sc]; w3 = xlb[(size_t)sc * 64 + lane]; }
  }

  for (int i = beg; i < end; ++i) {
    float e = as0 + adn;
    e = (e > 0.f) ? e : 0.2f * e;
    float vc = bflo((unsigned int)w0);
    as0 = as1; w0 = w1;                       // shift pipeline
    as1 = as2; w1 = w2;
    as2 = as3; w2 = w3;
    if (i + 4 < end) {
      int sc = col[i + 4];
      as3 = asrc[sc];
      w3 = xlb[(size_t)sc * 64 + lane];
    }
    float mn = fmaxf(m, e);
    float r = __expf(m - mn);
    float w = __expf(e - mn);
    s = fmaf(s, r, w);
    acc = fmaf(acc, r, w * vc);
    m = mn;
  }
  out[(size_t)n * 64 + lane] = fmaf(acc, 1.f / s, bias[lane]);
}

// ---------------------------------------------------------------------------

extern "C" void kernel_launch(void* const* d_in, const int* in_sizes, int n_in,
                              void* d_out, int out_size, void* d_ws, size_t ws_size,
                              hipStream_t stream) {
  const float* x   = (const float*)d_in[0];
  const int*   ei  = (const int*)d_in[1];
  const float* W1  = (const float*)d_in[2];
  const float* as1 = (const float*)d_in[3];
  const float* ad1 = (const float*)d_in[4];
  const float* b1  = (const float*)d_in[5];
  const float* W2  = (const float*)d_in[6];
  const float* as2 = (const float*)d_in[7];
  const float* ad2 = (const float*)d_in[8];
  const float* b2  = (const float*)d_in[9];
  float* out = (float*)d_out;

  const int Nn = in_sizes[0] / 128;  // 50000
  const int E  = in_sizes[1] / 2;    // 800000
  const int Et = E + Nn;
  const int Ntot = Nn + 1;           // scan domain (virtual deg[Nn]=0)
  const int NB = (Ntot + 1023) / 1024;
  const int MB = (Nn + 127) / 128;   // GEMM row blocks
  const int Mpad = MB * 128;         // padded rows so staging reads stay in-bounds

  char* base = (char*)d_ws;
  size_t off = 0;
  auto alloc = [&](size_t bytes) -> void* {
    void* p = base + off;
    off = (off + bytes + 255) & ~(size_t)255;
    return p;
  };
  u16*   xb       = (u16*)alloc((size_t)Mpad * 128 * 2);   // x, bf16
  u16*   w1t      = (u16*)alloc((size_t)256 * 128 * 2);    // W1^T bf16 [256][128]
  u16*   w2t      = (u16*)alloc((size_t)64 * 256 * 2);     // W2^T bf16 [64][256]
  u16*   xlb1     = (u16*)alloc((size_t)Mpad * 256 * 2);   // x@W1, bf16
  u16*   hb       = (u16*)alloc((size_t)Mpad * 256 * 2);   // ELU output, bf16
  float* asrc1    = (float*)alloc((size_t)Nn * 4 * 4);
  float* adst1    = (float*)alloc((size_t)Nn * 4 * 4);
  float* asrc2    = (float*)alloc((size_t)Nn * 4);
  float* adst2    = (float*)alloc((size_t)Nn * 4);
  int*   deg      = (int*)alloc((size_t)(Ntot + 8) * 4);
  int*   rowptr   = (int*)alloc((size_t)(Ntot + 8) * 4);
  int*   cursor   = (int*)alloc((size_t)(Ntot + 8) * 4);
  int*   partials = (int*)alloc(256 * 4);
  int*   col      = (int*)alloc((size_t)Et * 4);
  u16*   xlb2     = xlb1;  // layer2 h@W2 bf16 [Mpad][64], aliases xlb1

  // --- CSR build + input prep ---
  hipMemsetAsync(deg, 0, (size_t)Ntot * 4, stream);
  count_edges_kernel<<<(Et + 255) / 256, 256, 0, stream>>>(ei, E, Nn, deg);
  scan_partials_kernel<<<NB, 256, 0, stream>>>(deg, partials, Ntot);
  scan_top_kernel<<<1, 256, 0, stream>>>(partials, NB);
  scan_final_kernel<<<NB, 256, 0, stream>>>(deg, partials, rowptr, cursor, Ntot);
  scatter_edges_kernel<<<(Et + 255) / 256, 256, 0, stream>>>(ei, E, Nn, cursor, col);
  {
    int nx4 = Nn * 128 / 4;
    int tot = nx4 + 128 * 256 + 256 * 64;
    cast_prep_kernel<<<(tot + 255) / 256, 256, 0, stream>>>(
        x, xb, nx4, W1, w1t, 128, 256, W2, w2t, 256, 64);
  }

  // --- layer 1 ---
  {
    dim3 grid(MB, 2);
    gemm_mfma_kernel<128><<<grid, 256, 0, stream>>>(xb, w1t, xlb1, Nn, 128, 256);
  }
  alpha_kernel<<<(Nn * 4 + 255) / 256, 256, 0, stream>>>(xlb1, as1, ad1, asrc1, adst1, Nn * 4, 4, 64);
  agg_multi_kernel<<<(Nn + 3) / 4, 256, 0, stream>>>(xlb1, asrc1, adst1, rowptr, col, b1, hb, Nn);

  // --- layer 2 ---
  {
    dim3 grid(MB, 1);
    gemm_mfma_kernel<64><<<grid, 256, 0, stream>>>(hb, w2t, xlb2, Nn, 256, 64);
  }
  alpha_kernel<<<(Nn + 255) / 256, 256, 0, stream>>>(xlb2, as2, ad2, asrc2, adst2, Nn, 1, 64);
  agg_single_kernel<<<(Nn + 3) / 4, 256, 0, stream>>>(xlb2, asrc2, adst2, rowptr, col, b2, out, Nn);
}